// Round 1
// baseline (366.047 us; speedup 1.0000x reference)
//
#include <hip/hip_runtime.h>
#include <hip/hip_bf16.h>
#include <math.h>

#define N_NODES 16384
#define D_MODEL 256
#define H_HEADS 4
#define C_CH 256
#define E_EDGES 65536
#define ETOT (E_EDGES + N_NODES)
#define HC (H_HEADS * C_CH) /* 1024 */

// ---------------- LayerNorm: one row per wave ----------------
__global__ __launch_bounds__(256) void ln_kernel(
    const float* __restrict__ in, const float* __restrict__ gamma,
    const float* __restrict__ beta, float* __restrict__ out)
{
    int wave = threadIdx.x >> 6;
    int lane = threadIdx.x & 63;
    int row  = blockIdx.x * 4 + wave;
    const float4* pin = (const float4*)(in + (size_t)row * D_MODEL);
    float4 v = pin[lane];
    float s  = v.x + v.y + v.z + v.w;
    float sq = v.x*v.x + v.y*v.y + v.z*v.z + v.w*v.w;
    for (int off = 32; off; off >>= 1) {
        s  += __shfl_xor(s,  off);
        sq += __shfl_xor(sq, off);
    }
    float mean = s * (1.0f / D_MODEL);
    float var  = sq * (1.0f / D_MODEL) - mean * mean;
    float inv  = rsqrtf(var + 1e-6f);
    float4 g = ((const float4*)gamma)[lane];
    float4 b = ((const float4*)beta)[lane];
    float4 o;
    o.x = (v.x - mean) * inv * g.x + b.x;
    o.y = (v.y - mean) * inv * g.y + b.y;
    o.z = (v.z - mean) * inv * g.z + b.z;
    o.w = (v.w - mean) * inv * g.w + b.w;
    ((float4*)(out + (size_t)row * D_MODEL))[lane] = o;
}

// ---------------- fp32 tiled GEMM: C[M,N] = A[M,K] * B[N,K]^T (+bias +resid) ----
#define BM 64
#define BN 64
#define BK 16
#define LDP 68  // padded leading dim: 272 B keeps 16B alignment, breaks bank conflicts

__global__ __launch_bounds__(256) void gemm_nt(
    const float* __restrict__ A, const float* __restrict__ B,
    float* __restrict__ Cout, const float* __restrict__ bias,
    const float* __restrict__ resid, int M, int N, int K)
{
    __shared__ float As[BK][LDP];
    __shared__ float Bs[BK][LDP];
    int tid = threadIdx.x;
    int tx = tid & 15, ty = tid >> 4;
    int m0 = blockIdx.y * BM;
    int n0 = blockIdx.x * BN;
    int lr = tid >> 2;         // 0..63
    int lc = (tid & 3) << 2;   // 0,4,8,12
    float acc[4][4] = {};
    for (int kb = 0; kb < K; kb += BK) {
        float4 av = *(const float4*)(A + (size_t)(m0 + lr) * K + kb + lc);
        float4 bv = *(const float4*)(B + (size_t)(n0 + lr) * K + kb + lc);
        __syncthreads();   // previous iteration's reads done
        As[lc+0][lr] = av.x; As[lc+1][lr] = av.y; As[lc+2][lr] = av.z; As[lc+3][lr] = av.w;
        Bs[lc+0][lr] = bv.x; Bs[lc+1][lr] = bv.y; Bs[lc+2][lr] = bv.z; Bs[lc+3][lr] = bv.w;
        __syncthreads();
        #pragma unroll
        for (int k = 0; k < BK; ++k) {
            float4 a = *(const float4*)&As[k][ty*4];
            float4 b = *(const float4*)&Bs[k][tx*4];
            float ar[4] = {a.x, a.y, a.z, a.w};
            float br[4] = {b.x, b.y, b.z, b.w};
            #pragma unroll
            for (int i = 0; i < 4; ++i)
                #pragma unroll
                for (int j = 0; j < 4; ++j)
                    acc[i][j] = fmaf(ar[i], br[j], acc[i][j]);
        }
    }
    float4 bb = make_float4(0.f, 0.f, 0.f, 0.f);
    if (bias) bb = *(const float4*)(bias + n0 + tx*4);
    #pragma unroll
    for (int i = 0; i < 4; ++i) {
        int row = m0 + ty*4 + i;
        size_t off = (size_t)row * N + n0 + tx*4;
        float4 o = make_float4(acc[i][0]+bb.x, acc[i][1]+bb.y, acc[i][2]+bb.z, acc[i][3]+bb.w);
        if (resid) {
            float4 r = *(const float4*)(resid + off);
            o.x += r.x; o.y += r.y; o.z += r.z; o.w += r.w;
        }
        *(float4*)(Cout + off) = o;
    }
}

// ---------------- per-(node,head) attention logits: one wave each ----------------
__global__ __launch_bounds__(256) void att_logits(
    const float* __restrict__ xh, const float* __restrict__ att_src,
    const float* __restrict__ att_dst, float* __restrict__ a_src,
    float* __restrict__ a_dst)
{
    int wave = threadIdx.x >> 6, lane = threadIdx.x & 63;
    int wg = blockIdx.x * 4 + wave;   // n*H + h
    int n = wg >> 2, h = wg & 3;
    const float4* px = (const float4*)(xh + (size_t)n * HC + h * C_CH);
    const float4* ps = (const float4*)(att_src + h * C_CH);
    const float4* pd = (const float4*)(att_dst + h * C_CH);
    float4 x = px[lane], sv = ps[lane], dv = pd[lane];
    float s = x.x*sv.x + x.y*sv.y + x.z*sv.z + x.w*sv.w;
    float d = x.x*dv.x + x.y*dv.y + x.z*dv.z + x.w*dv.w;
    for (int off = 32; off; off >>= 1) {
        s += __shfl_xor(s, off);
        d += __shfl_xor(d, off);
    }
    if (lane == 0) { a_src[wg] = s; a_dst[wg] = d; }
}

// ---------------- CSR build ----------------
__global__ void hist_kernel(const int* __restrict__ ei, int* __restrict__ deg)
{
    int e = blockIdx.x * blockDim.x + threadIdx.x;
    if (e >= ETOT) return;
    int dst = (e < E_EDGES) ? ei[E_EDGES + e] : (e - E_EDGES);
    atomicAdd(deg + dst, 1);
}

__global__ __launch_bounds__(1024) void scan_kernel(
    const int* __restrict__ deg, int* __restrict__ row_start)
{
    __shared__ int sdata[1024];
    int tid = threadIdx.x;
    int base = tid * 16;
    int local[16];
    int run = 0;
    #pragma unroll
    for (int j = 0; j < 16; ++j) { local[j] = run; run += deg[base + j]; }
    sdata[tid] = run;
    __syncthreads();
    for (int off = 1; off < 1024; off <<= 1) {
        int v = 0;
        if (tid >= off) v = sdata[tid - off];
        __syncthreads();
        sdata[tid] += v;
        __syncthreads();
    }
    int pre = sdata[tid] - run;  // exclusive prefix of this thread's chunk
    #pragma unroll
    for (int j = 0; j < 16; ++j) row_start[base + j] = pre + local[j];
    if (tid == 1023) row_start[N_NODES] = sdata[1023];
}

__global__ void scatter_kernel(const int* __restrict__ ei,
                               const int* __restrict__ row_start,
                               int* __restrict__ cnt, int* __restrict__ csr_src)
{
    int e = blockIdx.x * blockDim.x + threadIdx.x;
    if (e >= ETOT) return;
    int src, dst;
    if (e < E_EDGES) { src = ei[e]; dst = ei[E_EDGES + e]; }
    else             { src = dst = e - E_EDGES; }
    int pos = atomicAdd(cnt + dst, 1);
    csr_src[row_start[dst] + pos] = src;
}

// ---------------- per-node softmax + aggregation (one block per node) ----------------
__global__ __launch_bounds__(256) void gat_aggregate(
    const float* __restrict__ xh, const float* __restrict__ a_src,
    const float* __restrict__ a_dst, const int* __restrict__ row_start,
    const int* __restrict__ csr_src, const float* __restrict__ bias,
    float* __restrict__ out)
{
    int i = blockIdx.x;
    int tid = threadIdx.x;
    int lane = tid & 63, wid = tid >> 6;
    int rs = row_start[i], re = row_start[i + 1];
    int deg = re - rs;
    float adst[H_HEADS];
    #pragma unroll
    for (int h = 0; h < H_HEADS; ++h) adst[h] = a_dst[i*H_HEADS + h];

    __shared__ float sred[H_HEADS][4];

    // pass 1: per-head max logit
    float mx[H_HEADS] = {-1e30f, -1e30f, -1e30f, -1e30f};
    for (int e = tid; e < deg; e += 256) {
        int s = csr_src[rs + e];
        #pragma unroll
        for (int h = 0; h < H_HEADS; ++h) {
            float l = a_src[s*H_HEADS + h] + adst[h];
            l = (l > 0.f) ? l : 0.2f * l;
            mx[h] = fmaxf(mx[h], l);
        }
    }
    #pragma unroll
    for (int h = 0; h < H_HEADS; ++h)
        for (int off = 32; off; off >>= 1) mx[h] = fmaxf(mx[h], __shfl_xor(mx[h], off));
    if (lane == 0) {
        #pragma unroll
        for (int h = 0; h < H_HEADS; ++h) sred[h][wid] = mx[h];
    }
    __syncthreads();
    float MX[H_HEADS];
    #pragma unroll
    for (int h = 0; h < H_HEADS; ++h)
        MX[h] = fmaxf(fmaxf(sred[h][0], sred[h][1]), fmaxf(sred[h][2], sred[h][3]));
    __syncthreads();

    // pass 2: per-head sum of exp
    float sm[H_HEADS] = {0.f, 0.f, 0.f, 0.f};
    for (int e = tid; e < deg; e += 256) {
        int s = csr_src[rs + e];
        #pragma unroll
        for (int h = 0; h < H_HEADS; ++h) {
            float l = a_src[s*H_HEADS + h] + adst[h];
            l = (l > 0.f) ? l : 0.2f * l;
            sm[h] += expf(l - MX[h]);
        }
    }
    #pragma unroll
    for (int h = 0; h < H_HEADS; ++h)
        for (int off = 32; off; off >>= 1) sm[h] += __shfl_xor(sm[h], off);
    if (lane == 0) {
        #pragma unroll
        for (int h = 0; h < H_HEADS; ++h) sred[h][wid] = sm[h];
    }
    __syncthreads();
    float inv[H_HEADS];
    #pragma unroll
    for (int h = 0; h < H_HEADS; ++h)
        inv[h] = 1.0f / (sred[h][0] + sred[h][1] + sred[h][2] + sred[h][3]);

    // pass 3: weighted gather-accumulate; thread owns channel c = tid
    float acc = 0.f;
    int c = tid;
    for (int e = 0; e < deg; ++e) {
        int s = csr_src[rs + e];
        float w[H_HEADS];
        #pragma unroll
        for (int h = 0; h < H_HEADS; ++h) {
            float l = a_src[s*H_HEADS + h] + adst[h];
            l = (l > 0.f) ? l : 0.2f * l;
            w[h] = expf(l - MX[h]) * inv[h];
        }
        const float* xp = xh + (size_t)s * HC;
        acc += w[0]*xp[c] + w[1]*xp[C_CH + c] + w[2]*xp[2*C_CH + c] + w[3]*xp[3*C_CH + c];
    }
    out[(size_t)i * C_CH + c] = acc * (1.0f / H_HEADS) + bias[c];
}

extern "C" void kernel_launch(void* const* d_in, const int* in_sizes, int n_in,
                              void* d_out, int out_size, void* d_ws, size_t ws_size,
                              hipStream_t stream)
{
    const float* inp      = (const float*)d_in[0];
    const int*   ei       = (const int*)  d_in[1];
    const float* ln_gamma = (const float*)d_in[2];
    const float* ln_beta  = (const float*)d_in[3];
    const float* W1       = (const float*)d_in[4];
    const float* b1       = (const float*)d_in[5];
    const float* W_gat    = (const float*)d_in[6];
    const float* att_src  = (const float*)d_in[7];
    const float* att_dst  = (const float*)d_in[8];
    const float* bias_gat = (const float*)d_in[9];
    const float* W2       = (const float*)d_in[10];
    const float* b2       = (const float*)d_in[11];

    char* ws = (char*)d_ws;
    float* xh      = (float*)ws;                             // 64 MB
    float* x_ln    = (float*)(ws + ((size_t)64 << 20));      // 16 MB (reused as gnn_out)
    float* gnn_in  = (float*)(ws + ((size_t)80 << 20));      // 16 MB
    float* a_src_b = (float*)(ws + ((size_t)96 << 20));      // 256 KB
    float* a_dst_b = a_src_b + (size_t)N_NODES * H_HEADS;    // 256 KB
    int*   deg     = (int*)(a_dst_b + (size_t)N_NODES * H_HEADS);
    int*   row_st  = deg + N_NODES;
    int*   cnt     = row_st + N_NODES + 4;
    int*   csr_src = cnt + N_NODES;

    // CSR build (independent of the dense pipeline)
    hipMemsetAsync(deg, 0, N_NODES * sizeof(int), stream);
    hipMemsetAsync(cnt, 0, N_NODES * sizeof(int), stream);
    hist_kernel<<<(ETOT + 255) / 256, 256, 0, stream>>>(ei, deg);
    scan_kernel<<<1, 1024, 0, stream>>>(deg, row_st);
    scatter_kernel<<<(ETOT + 255) / 256, 256, 0, stream>>>(ei, row_st, cnt, csr_src);

    // dense pipeline
    ln_kernel<<<N_NODES / 4, 256, 0, stream>>>(inp, ln_gamma, ln_beta, x_ln);
    gemm_nt<<<dim3(D_MODEL / BN, N_NODES / BM), 256, 0, stream>>>(
        x_ln, W1, gnn_in, b1, nullptr, N_NODES, D_MODEL, D_MODEL);
    gemm_nt<<<dim3(HC / BN, N_NODES / BM), 256, 0, stream>>>(
        gnn_in, W_gat, xh, nullptr, nullptr, N_NODES, HC, D_MODEL);
    att_logits<<<N_NODES * H_HEADS / 4, 256, 0, stream>>>(xh, att_src, att_dst, a_src_b, a_dst_b);
    gat_aggregate<<<N_NODES, 256, 0, stream>>>(xh, a_src_b, a_dst_b, row_st, csr_src,
                                               bias_gat, x_ln /* gnn_out, reuse */);
    gemm_nt<<<dim3(D_MODEL / BN, N_NODES / BM), 256, 0, stream>>>(
        x_ln, W2, (float*)d_out, b2, inp, N_NODES, D_MODEL, D_MODEL);
}

// Round 2
// 255.220 us; speedup vs baseline: 1.4342x; 1.4342x over previous
//
#include <hip/hip_runtime.h>
#include <math.h>

#define N_NODES 16384
#define D_MODEL 256
#define H_HEADS 4
#define C_CH 256
#define E_EDGES 65536
#define ETOT (E_EDGES + N_NODES)
#define HC 1024

typedef __bf16 bf16x8 __attribute__((ext_vector_type(8)));
typedef __bf16 bf16x4 __attribute__((ext_vector_type(4)));
typedef float f32x4 __attribute__((ext_vector_type(4)));

__device__ __forceinline__ __bf16 f2bf(float f) { return (__bf16)f; }
__device__ __forceinline__ float bf2f(__bf16 b) { return (float)b; }

// ---------------- generic fp32 -> bf16 cast (n % 4 == 0) ----------------
__global__ __launch_bounds__(256) void cast_f2b(const float* __restrict__ src,
                                                __bf16* __restrict__ dst, int n)
{
    int i = (blockIdx.x * 256 + threadIdx.x) * 4;
    if (i >= n) return;
    float4 v = *(const float4*)(src + i);
    bf16x4 o;
    o[0] = f2bf(v.x); o[1] = f2bf(v.y); o[2] = f2bf(v.z); o[3] = f2bf(v.w);
    *(bf16x4*)(dst + i) = o;
}

// ---------------- LayerNorm: one row per wave, bf16 out ----------------
__global__ __launch_bounds__(256) void ln_kernel(
    const float* __restrict__ in, const float* __restrict__ gamma,
    const float* __restrict__ beta, __bf16* __restrict__ out)
{
    int wave = threadIdx.x >> 6;
    int lane = threadIdx.x & 63;
    int row  = blockIdx.x * 4 + wave;
    float4 v = ((const float4*)(in + (size_t)row * D_MODEL))[lane];
    float s  = v.x + v.y + v.z + v.w;
    float sq = v.x*v.x + v.y*v.y + v.z*v.z + v.w*v.w;
    for (int off = 32; off; off >>= 1) {
        s  += __shfl_xor(s,  off);
        sq += __shfl_xor(sq, off);
    }
    float mean = s * (1.0f / D_MODEL);
    float var  = sq * (1.0f / D_MODEL) - mean * mean;
    float inv  = rsqrtf(var + 1e-6f);
    float4 g = ((const float4*)gamma)[lane];
    float4 b = ((const float4*)beta)[lane];
    bf16x4 o;
    o[0] = f2bf((v.x - mean) * inv * g.x + b.x);
    o[1] = f2bf((v.y - mean) * inv * g.y + b.y);
    o[2] = f2bf((v.z - mean) * inv * g.z + b.z);
    o[3] = f2bf((v.w - mean) * inv * g.w + b.w);
    *(bf16x4*)(out + (size_t)row * D_MODEL + lane * 4) = o;
}

// -------- bf16 MFMA GEMM: C[M,N] = A[M,K] * B[N,K]^T (+bias)(+resid) --------
// 128x128 block tile, 4 waves (2x2), each wave 64x64 via 4x4 mfma 16x16x32 tiles.
#define BM 128
#define BN 128
#define BK 32
#define LDP 40   // LDS row stride in bf16 elems (80B): 2-way-max bank aliasing (free)

__global__ __launch_bounds__(256) void gemm_bf16_nt(
    const __bf16* __restrict__ A, const __bf16* __restrict__ B,
    int M, int N, int K,
    const float* __restrict__ bias, const float* __restrict__ resid,
    float* __restrict__ outf, __bf16* __restrict__ outb)
{
    __shared__ __bf16 As[BM * LDP];
    __shared__ __bf16 Bs[BN * LDP];
    int tid  = threadIdx.x;
    int lane = tid & 63;
    int w    = tid >> 6;
    int wm   = w >> 1, wn = w & 1;
    int quad = lane >> 4;   // 0..3
    int l16  = lane & 15;
    int m0 = blockIdx.y * BM;
    int n0 = blockIdx.x * BN;

    f32x4 acc[4][4] = {};

    for (int kb = 0; kb < K; kb += BK) {
        // stage 128x32 A-tile and B-tile: 512 16B-chunks, 2 per thread
        bf16x8 areg[2], breg[2];
        #pragma unroll
        for (int t = 0; t < 2; ++t) {
            int c = tid + t * 256;
            int r = c >> 2, p = c & 3;
            areg[t] = *(const bf16x8*)(A + (size_t)(m0 + r) * K + kb + p * 8);
            breg[t] = *(const bf16x8*)(B + (size_t)(n0 + r) * K + kb + p * 8);
        }
        __syncthreads();   // previous iteration's LDS reads complete
        #pragma unroll
        for (int t = 0; t < 2; ++t) {
            int c = tid + t * 256;
            int r = c >> 2, p = c & 3;
            *(bf16x8*)(As + r * LDP + p * 8) = areg[t];
            *(bf16x8*)(Bs + r * LDP + p * 8) = breg[t];
        }
        __syncthreads();
        // fragments: A[m=l16][k=quad*8+j], B[n=l16][k=quad*8+j]
        bf16x8 af[4], bfr[4];
        #pragma unroll
        for (int mt = 0; mt < 4; ++mt)
            af[mt] = *(const bf16x8*)(As + (wm * 64 + mt * 16 + l16) * LDP + quad * 8);
        #pragma unroll
        for (int nt = 0; nt < 4; ++nt)
            bfr[nt] = *(const bf16x8*)(Bs + (wn * 64 + nt * 16 + l16) * LDP + quad * 8);
        #pragma unroll
        for (int mt = 0; mt < 4; ++mt)
            #pragma unroll
            for (int nt = 0; nt < 4; ++nt)
                acc[mt][nt] = __builtin_amdgcn_mfma_f32_16x16x32_bf16(
                    af[mt], bfr[nt], acc[mt][nt], 0, 0, 0);
    }

    // epilogue: D layout col=lane&15, row=quad*4+reg
    int rowb = m0 + wm * 64;
    int colb = n0 + wn * 64;
    #pragma unroll
    for (int nt = 0; nt < 4; ++nt) {
        int col = colb + nt * 16 + l16;
        float bv = bias ? bias[col] : 0.0f;
        #pragma unroll
        for (int mt = 0; mt < 4; ++mt) {
            int row = rowb + mt * 16 + quad * 4;
            #pragma unroll
            for (int r = 0; r < 4; ++r) {
                float v = acc[mt][nt][r] + bv;
                size_t off = (size_t)(row + r) * N + col;
                if (outf) {
                    if (resid) v += resid[off];
                    outf[off] = v;
                } else {
                    outb[off] = f2bf(v);
                }
            }
        }
    }
}

// ------- per-node attention logits: one wave per node, all 4 heads -------
__global__ __launch_bounds__(256) void att_logits(
    const __bf16* __restrict__ xh, const float* __restrict__ att_src,
    const float* __restrict__ att_dst, float* __restrict__ a_src,
    float* __restrict__ a_dst)
{
    int wave = threadIdx.x >> 6, lane = threadIdx.x & 63;
    int n = blockIdx.x * 4 + wave;
    int h = lane >> 4;
    // lane covers 16 channels; flat offset lane*16 matches [H][C] layout
    const __bf16* xp = xh + (size_t)n * HC + lane * 16;
    float s = 0.f, d = 0.f;
    #pragma unroll
    for (int t = 0; t < 2; ++t) {
        bf16x8 x = *(const bf16x8*)(xp + t * 8);
        const float* sp = att_src + lane * 16 + t * 8;
        const float* dp = att_dst + lane * 16 + t * 8;
        #pragma unroll
        for (int j = 0; j < 8; ++j) {
            float xv = bf2f(x[j]);
            s += xv * sp[j];
            d += xv * dp[j];
        }
    }
    // reduce within 16-lane groups
    for (int off = 1; off < 16; off <<= 1) {
        s += __shfl_xor(s, off);
        d += __shfl_xor(d, off);
    }
    if ((lane & 15) == 0) {
        a_src[n * H_HEADS + h] = s;
        a_dst[n * H_HEADS + h] = d;
    }
}

// ---------------- CSR build ----------------
__global__ void hist_kernel(const int* __restrict__ ei, int* __restrict__ deg)
{
    int e = blockIdx.x * blockDim.x + threadIdx.x;
    if (e >= ETOT) return;
    int dst = (e < E_EDGES) ? ei[E_EDGES + e] : (e - E_EDGES);
    atomicAdd(deg + dst, 1);
}

__global__ __launch_bounds__(1024) void scan_kernel(
    const int* __restrict__ deg, int* __restrict__ row_start)
{
    __shared__ int sdata[1024];
    int tid = threadIdx.x;
    int base = tid * 16;
    int local[16];
    int run = 0;
    #pragma unroll
    for (int j = 0; j < 16; ++j) { local[j] = run; run += deg[base + j]; }
    sdata[tid] = run;
    __syncthreads();
    for (int off = 1; off < 1024; off <<= 1) {
        int v = 0;
        if (tid >= off) v = sdata[tid - off];
        __syncthreads();
        sdata[tid] += v;
        __syncthreads();
    }
    int pre = sdata[tid] - run;
    #pragma unroll
    for (int j = 0; j < 16; ++j) row_start[base + j] = pre + local[j];
    if (tid == 1023) row_start[N_NODES] = sdata[1023];
}

__global__ void scatter_kernel(const int* __restrict__ ei,
                               const int* __restrict__ row_start,
                               int* __restrict__ cnt, int* __restrict__ csr_src)
{
    int e = blockIdx.x * blockDim.x + threadIdx.x;
    if (e >= ETOT) return;
    int src, dst;
    if (e < E_EDGES) { src = ei[e]; dst = ei[E_EDGES + e]; }
    else             { src = dst = e - E_EDGES; }
    int pos = atomicAdd(cnt + dst, 1);
    csr_src[row_start[dst] + pos] = src;
}

// ------- per-node softmax + aggregation (one block per node), bf16 out -------
__global__ __launch_bounds__(256) void gat_aggregate(
    const __bf16* __restrict__ xh, const float* __restrict__ a_src,
    const float* __restrict__ a_dst, const int* __restrict__ row_start,
    const int* __restrict__ csr_src, const float* __restrict__ bias,
    __bf16* __restrict__ out)
{
    int i = blockIdx.x;
    int tid = threadIdx.x;
    int lane = tid & 63, wid = tid >> 6;
    int rs = row_start[i], re = row_start[i + 1];
    int deg = re - rs;
    float adst[H_HEADS];
    #pragma unroll
    for (int h = 0; h < H_HEADS; ++h) adst[h] = a_dst[i * H_HEADS + h];

    __shared__ float sred[H_HEADS][4];

    // pass 1: per-head max logit
    float mx[H_HEADS] = {-1e30f, -1e30f, -1e30f, -1e30f};
    for (int e = tid; e < deg; e += 256) {
        int s = csr_src[rs + e];
        #pragma unroll
        for (int h = 0; h < H_HEADS; ++h) {
            float l = a_src[s * H_HEADS + h] + adst[h];
            l = (l > 0.f) ? l : 0.2f * l;
            mx[h] = fmaxf(mx[h], l);
        }
    }
    #pragma unroll
    for (int h = 0; h < H_HEADS; ++h)
        for (int off = 32; off; off >>= 1) mx[h] = fmaxf(mx[h], __shfl_xor(mx[h], off));
    if (lane == 0) {
        #pragma unroll
        for (int h = 0; h < H_HEADS; ++h) sred[h][wid] = mx[h];
    }
    __syncthreads();
    float MX[H_HEADS];
    #pragma unroll
    for (int h = 0; h < H_HEADS; ++h)
        MX[h] = fmaxf(fmaxf(sred[h][0], sred[h][1]), fmaxf(sred[h][2], sred[h][3]));
    __syncthreads();

    // pass 2: per-head sum of exp
    float sm[H_HEADS] = {0.f, 0.f, 0.f, 0.f};
    for (int e = tid; e < deg; e += 256) {
        int s = csr_src[rs + e];
        #pragma unroll
        for (int h = 0; h < H_HEADS; ++h) {
            float l = a_src[s * H_HEADS + h] + adst[h];
            l = (l > 0.f) ? l : 0.2f * l;
            sm[h] += expf(l - MX[h]);
        }
    }
    #pragma unroll
    for (int h = 0; h < H_HEADS; ++h)
        for (int off = 32; off; off >>= 1) sm[h] += __shfl_xor(sm[h], off);
    if (lane == 0) {
        #pragma unroll
        for (int h = 0; h < H_HEADS; ++h) sred[h][wid] = sm[h];
    }
    __syncthreads();
    float inv[H_HEADS];
    #pragma unroll
    for (int h = 0; h < H_HEADS; ++h)
        inv[h] = 1.0f / (sred[h][0] + sred[h][1] + sred[h][2] + sred[h][3]);

    // pass 3: weighted gather; thread owns channel c = tid
    float acc = 0.f;
    int c = tid;
    for (int e = 0; e < deg; ++e) {
        int s = csr_src[rs + e];
        float w[H_HEADS];
        #pragma unroll
        for (int h = 0; h < H_HEADS; ++h) {
            float l = a_src[s * H_HEADS + h] + adst[h];
            l = (l > 0.f) ? l : 0.2f * l;
            w[h] = expf(l - MX[h]) * inv[h];
        }
        const __bf16* xp = xh + (size_t)s * HC;
        acc += w[0] * bf2f(xp[c]) + w[1] * bf2f(xp[C_CH + c])
             + w[2] * bf2f(xp[2 * C_CH + c]) + w[3] * bf2f(xp[3 * C_CH + c]);
    }
    out[(size_t)i * C_CH + c] = f2bf(acc * (1.0f / H_HEADS) + bias[c]);
}

extern "C" void kernel_launch(void* const* d_in, const int* in_sizes, int n_in,
                              void* d_out, int out_size, void* d_ws, size_t ws_size,
                              hipStream_t stream)
{
    const float* inp      = (const float*)d_in[0];
    const int*   ei       = (const int*)  d_in[1];
    const float* ln_gamma = (const float*)d_in[2];
    const float* ln_beta  = (const float*)d_in[3];
    const float* W1       = (const float*)d_in[4];
    const float* b1       = (const float*)d_in[5];
    const float* W_gat    = (const float*)d_in[6];
    const float* att_src  = (const float*)d_in[7];
    const float* att_dst  = (const float*)d_in[8];
    const float* bias_gat = (const float*)d_in[9];
    const float* W2       = (const float*)d_in[10];
    const float* b2       = (const float*)d_in[11];

    char* ws = (char*)d_ws;
    __bf16* x_ln_bf   = (__bf16*)(ws);                        //  8 MB
    __bf16* gnn_in_bf = (__bf16*)(ws + ((size_t) 8 << 20));   //  8 MB
    __bf16* xh_bf     = (__bf16*)(ws + ((size_t)16 << 20));   // 32 MB
    __bf16* gnn_out_bf= (__bf16*)(ws + ((size_t)48 << 20));   //  8 MB
    __bf16* W1_bf     = (__bf16*)(ws + ((size_t)56 << 20));   // 128 KB
    __bf16* Wgat_bf   = W1_bf + 65536;                        // 512 KB
    __bf16* W2_bf     = Wgat_bf + 262144;                     // 128 KB
    float*  a_src_b   = (float*)(ws + ((size_t)57 << 20));    // 256 KB
    float*  a_dst_b   = a_src_b + (size_t)N_NODES * H_HEADS;  // 256 KB
    int*    deg       = (int*)(a_dst_b + (size_t)N_NODES * H_HEADS);
    int*    row_st    = deg + N_NODES;
    int*    cnt       = row_st + N_NODES + 4;
    int*    csr_src   = cnt + N_NODES;

    // weight casts + CSR build (independent of dense pipeline head)
    cast_f2b<<<64,  256, 0, stream>>>(W1,    W1_bf,   65536);
    cast_f2b<<<256, 256, 0, stream>>>(W_gat, Wgat_bf, 262144);
    cast_f2b<<<64,  256, 0, stream>>>(W2,    W2_bf,   65536);
    hipMemsetAsync(deg, 0, N_NODES * sizeof(int), stream);
    hipMemsetAsync(cnt, 0, N_NODES * sizeof(int), stream);
    hist_kernel<<<(ETOT + 255) / 256, 256, 0, stream>>>(ei, deg);
    scan_kernel<<<1, 1024, 0, stream>>>(deg, row_st);
    scatter_kernel<<<(ETOT + 255) / 256, 256, 0, stream>>>(ei, row_st, cnt, csr_src);

    // dense pipeline
    ln_kernel<<<N_NODES / 4, 256, 0, stream>>>(inp, ln_gamma, ln_beta, x_ln_bf);
    gemm_bf16_nt<<<dim3(D_MODEL / BN, N_NODES / BM), 256, 0, stream>>>(
        x_ln_bf, W1_bf, N_NODES, D_MODEL, D_MODEL, b1, nullptr, nullptr, gnn_in_bf);
    gemm_bf16_nt<<<dim3(HC / BN, N_NODES / BM), 256, 0, stream>>>(
        gnn_in_bf, Wgat_bf, N_NODES, HC, D_MODEL, nullptr, nullptr, nullptr, xh_bf);
    att_logits<<<N_NODES / 4, 256, 0, stream>>>(xh_bf, att_src, att_dst, a_src_b, a_dst_b);
    gat_aggregate<<<N_NODES, 256, 0, stream>>>(xh_bf, a_src_b, a_dst_b, row_st, csr_src,
                                               bias_gat, gnn_out_bf);
    gemm_bf16_nt<<<dim3(D_MODEL / BN, N_NODES / BM), 256, 0, stream>>>(
        gnn_out_bf, W2_bf, N_NODES, D_MODEL, D_MODEL, b2, inp, (float*)d_out, nullptr);
}

// Round 3
// 222.410 us; speedup vs baseline: 1.6458x; 1.1475x over previous
//
#include <hip/hip_runtime.h>
#include <math.h>

#define N_NODES 16384
#define D_MODEL 256
#define H_HEADS 4
#define C_CH 256
#define E_EDGES 65536
#define ETOT (E_EDGES + N_NODES)
#define HC 1024

typedef __bf16 bf16x8 __attribute__((ext_vector_type(8)));
typedef __bf16 bf16x4 __attribute__((ext_vector_type(4)));
typedef float f32x4 __attribute__((ext_vector_type(4)));

__device__ __forceinline__ __bf16 f2bf(float f) { return (__bf16)f; }
__device__ __forceinline__ float bf2f(__bf16 b) { return (float)b; }

// ---------------- fused weight cast: W1 | W_gat | W2 ----------------
__global__ __launch_bounds__(256) void cast_weights(
    const float* __restrict__ W1, const float* __restrict__ Wg,
    const float* __restrict__ W2, __bf16* __restrict__ o1,
    __bf16* __restrict__ og, __bf16* __restrict__ o2)
{
    int i = (blockIdx.x * 256 + threadIdx.x) * 4;
    const float* src; __bf16* dst; int off;
    if (i < 65536)            { src = W1; dst = o1; off = i; }
    else if (i < 65536+262144){ src = Wg; dst = og; off = i - 65536; }
    else                      { src = W2; dst = o2; off = i - 65536 - 262144; }
    float4 v = *(const float4*)(src + off);
    bf16x4 o;
    o[0] = f2bf(v.x); o[1] = f2bf(v.y); o[2] = f2bf(v.z); o[3] = f2bf(v.w);
    *(bf16x4*)(dst + off) = o;
}

// ---------------- LayerNorm: one row per wave, bf16 out ----------------
__global__ __launch_bounds__(256) void ln_kernel(
    const float* __restrict__ in, const float* __restrict__ gamma,
    const float* __restrict__ beta, __bf16* __restrict__ out)
{
    int wave = threadIdx.x >> 6;
    int lane = threadIdx.x & 63;
    int row  = blockIdx.x * 4 + wave;
    float4 v = ((const float4*)(in + (size_t)row * D_MODEL))[lane];
    float s  = v.x + v.y + v.z + v.w;
    float sq = v.x*v.x + v.y*v.y + v.z*v.z + v.w*v.w;
    for (int off = 32; off; off >>= 1) {
        s  += __shfl_xor(s,  off);
        sq += __shfl_xor(sq, off);
    }
    float mean = s * (1.0f / D_MODEL);
    float var  = sq * (1.0f / D_MODEL) - mean * mean;
    float inv  = rsqrtf(var + 1e-6f);
    float4 g = ((const float4*)gamma)[lane];
    float4 b = ((const float4*)beta)[lane];
    bf16x4 o;
    o[0] = f2bf((v.x - mean) * inv * g.x + b.x);
    o[1] = f2bf((v.y - mean) * inv * g.y + b.y);
    o[2] = f2bf((v.z - mean) * inv * g.z + b.z);
    o[3] = f2bf((v.w - mean) * inv * g.w + b.w);
    *(bf16x4*)(out + (size_t)row * D_MODEL + lane * 4) = o;
}

// -------- bf16 MFMA GEMM: C[M,N] = A[M,K] * B[N,K]^T (+bias)(+resid) --------
#define BM 128
#define BN 128
#define BK 32
#define LDP 40   // LDS row stride (80B): max 2-way bank aliasing (free)

__global__ __launch_bounds__(256) void gemm_bf16_nt(
    const __bf16* __restrict__ A, const __bf16* __restrict__ B,
    int M, int N, int K,
    const float* __restrict__ bias, const float* __restrict__ resid,
    float* __restrict__ outf, __bf16* __restrict__ outb)
{
    __shared__ __bf16 As[BM * LDP];
    __shared__ __bf16 Bs[BN * LDP];
    int tid  = threadIdx.x;
    int lane = tid & 63;
    int w    = tid >> 6;
    int wm   = w >> 1, wn = w & 1;
    int quad = lane >> 4;
    int l16  = lane & 15;
    int m0 = blockIdx.y * BM;
    int n0 = blockIdx.x * BN;

    f32x4 acc[4][4] = {};

    for (int kb = 0; kb < K; kb += BK) {
        bf16x8 areg[2], breg[2];
        #pragma unroll
        for (int t = 0; t < 2; ++t) {
            int c = tid + t * 256;
            int r = c >> 2, p = c & 3;
            areg[t] = *(const bf16x8*)(A + (size_t)(m0 + r) * K + kb + p * 8);
            breg[t] = *(const bf16x8*)(B + (size_t)(n0 + r) * K + kb + p * 8);
        }
        __syncthreads();
        #pragma unroll
        for (int t = 0; t < 2; ++t) {
            int c = tid + t * 256;
            int r = c >> 2, p = c & 3;
            *(bf16x8*)(As + r * LDP + p * 8) = areg[t];
            *(bf16x8*)(Bs + r * LDP + p * 8) = breg[t];
        }
        __syncthreads();
        bf16x8 af[4], bfr[4];
        #pragma unroll
        for (int mt = 0; mt < 4; ++mt)
            af[mt] = *(const bf16x8*)(As + (wm * 64 + mt * 16 + l16) * LDP + quad * 8);
        #pragma unroll
        for (int nt = 0; nt < 4; ++nt)
            bfr[nt] = *(const bf16x8*)(Bs + (wn * 64 + nt * 16 + l16) * LDP + quad * 8);
        #pragma unroll
        for (int mt = 0; mt < 4; ++mt)
            #pragma unroll
            for (int nt = 0; nt < 4; ++nt)
                acc[mt][nt] = __builtin_amdgcn_mfma_f32_16x16x32_bf16(
                    af[mt], bfr[nt], acc[mt][nt], 0, 0, 0);
    }

    int rowb = m0 + wm * 64;
    int colb = n0 + wn * 64;
    #pragma unroll
    for (int nt = 0; nt < 4; ++nt) {
        int col = colb + nt * 16 + l16;
        float bv = bias ? bias[col] : 0.0f;
        #pragma unroll
        for (int mt = 0; mt < 4; ++mt) {
            int row = rowb + mt * 16 + quad * 4;
            #pragma unroll
            for (int r = 0; r < 4; ++r) {
                float v = acc[mt][nt][r] + bv;
                size_t off = (size_t)(row + r) * N + col;
                if (outf) {
                    if (resid) v += resid[off];
                    outf[off] = v;
                } else {
                    outb[off] = f2bf(v);
                }
            }
        }
    }
}

// ------- per-node attention logits: one wave per node, all 4 heads -------
__global__ __launch_bounds__(256) void att_logits(
    const __bf16* __restrict__ xh, const float* __restrict__ att_src,
    const float* __restrict__ att_dst, float* __restrict__ a_src,
    float* __restrict__ a_dst)
{
    int wave = threadIdx.x >> 6, lane = threadIdx.x & 63;
    int n = blockIdx.x * 4 + wave;
    int h = lane >> 4;
    const __bf16* xp = xh + (size_t)n * HC + lane * 16;
    float s = 0.f, d = 0.f;
    #pragma unroll
    for (int t = 0; t < 2; ++t) {
        bf16x8 x = *(const bf16x8*)(xp + t * 8);
        const float* sp = att_src + lane * 16 + t * 8;
        const float* dp = att_dst + lane * 16 + t * 8;
        #pragma unroll
        for (int j = 0; j < 8; ++j) {
            float xv = bf2f(x[j]);
            s += xv * sp[j];
            d += xv * dp[j];
        }
    }
    for (int off = 1; off < 16; off <<= 1) {
        s += __shfl_xor(s, off);
        d += __shfl_xor(d, off);
    }
    if ((lane & 15) == 0) {
        a_src[n * H_HEADS + h] = s;
        a_dst[n * H_HEADS + h] = d;
    }
}

// ---------------- CSR build ----------------
__global__ void hist_kernel(const int* __restrict__ ei, int* __restrict__ deg)
{
    int e = blockIdx.x * blockDim.x + threadIdx.x;
    if (e >= ETOT) return;
    int dst = (e < E_EDGES) ? ei[E_EDGES + e] : (e - E_EDGES);
    atomicAdd(deg + dst, 1);
}

__global__ __launch_bounds__(1024) void scan_kernel(
    const int* __restrict__ deg, int* __restrict__ row_start)
{
    __shared__ int sdata[1024];
    int tid = threadIdx.x;
    int base = tid * 16;
    int local[16];
    int run = 0;
    #pragma unroll
    for (int j = 0; j < 16; ++j) { local[j] = run; run += deg[base + j]; }
    sdata[tid] = run;
    __syncthreads();
    for (int off = 1; off < 1024; off <<= 1) {
        int v = 0;
        if (tid >= off) v = sdata[tid - off];
        __syncthreads();
        sdata[tid] += v;
        __syncthreads();
    }
    int pre = sdata[tid] - run;
    #pragma unroll
    for (int j = 0; j < 16; ++j) row_start[base + j] = pre + local[j];
    if (tid == 1023) row_start[N_NODES] = sdata[1023];
}

__global__ void scatter_kernel(const int* __restrict__ ei,
                               const int* __restrict__ row_start,
                               int* __restrict__ cnt, int* __restrict__ csr_src)
{
    int e = blockIdx.x * blockDim.x + threadIdx.x;
    if (e >= ETOT) return;
    int src, dst;
    if (e < E_EDGES) { src = ei[e]; dst = ei[E_EDGES + e]; }
    else             { src = dst = e - E_EDGES; }
    int pos = atomicAdd(cnt + dst, 1);
    csr_src[row_start[dst] + pos] = src;
}

// ------- per-node softmax: one WAVE per node; writes unnormalized alpha -------
__global__ __launch_bounds__(256) void node_softmax(
    const float* __restrict__ a_src, const float* __restrict__ a_dst,
    const int* __restrict__ row_start, const int* __restrict__ csr_src,
    float* __restrict__ alpha, float* __restrict__ inv_denom)
{
    int wave = threadIdx.x >> 6, lane = threadIdx.x & 63;
    int i = blockIdx.x * 4 + wave;
    int rs = row_start[i], deg = row_start[i + 1] - rs;
    float adst[H_HEADS];
    #pragma unroll
    for (int h = 0; h < H_HEADS; ++h) adst[h] = a_dst[i * H_HEADS + h];

    float mx[H_HEADS] = {-1e30f, -1e30f, -1e30f, -1e30f};
    for (int e = lane; e < deg; e += 64) {
        int s = csr_src[rs + e];
        float4 as = *(const float4*)(a_src + s * H_HEADS);
        float l[H_HEADS] = {as.x + adst[0], as.y + adst[1], as.z + adst[2], as.w + adst[3]};
        #pragma unroll
        for (int h = 0; h < H_HEADS; ++h) {
            float v = (l[h] > 0.f) ? l[h] : 0.2f * l[h];
            mx[h] = fmaxf(mx[h], v);
        }
    }
    #pragma unroll
    for (int h = 0; h < H_HEADS; ++h)
        for (int off = 32; off; off >>= 1) mx[h] = fmaxf(mx[h], __shfl_xor(mx[h], off));

    float sm[H_HEADS] = {0.f, 0.f, 0.f, 0.f};
    for (int e = lane; e < deg; e += 64) {
        int s = csr_src[rs + e];
        float4 as = *(const float4*)(a_src + s * H_HEADS);
        float l[H_HEADS] = {as.x + adst[0], as.y + adst[1], as.z + adst[2], as.w + adst[3]};
        float4 wv;
        #pragma unroll
        for (int h = 0; h < H_HEADS; ++h) {
            float v = (l[h] > 0.f) ? l[h] : 0.2f * l[h];
            float w = expf(v - mx[h]);
            sm[h] += w;
            ((float*)&wv)[h] = w;
        }
        *(float4*)(alpha + (size_t)(rs + e) * H_HEADS) = wv;
    }
    #pragma unroll
    for (int h = 0; h < H_HEADS; ++h)
        for (int off = 32; off; off >>= 1) sm[h] += __shfl_xor(sm[h], off);
    if (lane == 0) {
        #pragma unroll
        for (int h = 0; h < H_HEADS; ++h)
            inv_denom[i * H_HEADS + h] = 1.0f / sm[h];
    }
}

// ------- aggregation: block per node; thread = (head, channel-quad) -------
__global__ __launch_bounds__(256) void gat_aggregate(
    const __bf16* __restrict__ xh, const float* __restrict__ alpha,
    const float* __restrict__ inv_denom, const int* __restrict__ row_start,
    const int* __restrict__ csr_src, const float* __restrict__ bias,
    __bf16* __restrict__ out)
{
    int i = blockIdx.x;
    int tid = threadIdx.x;
    int h  = tid >> 6;          // head 0..3
    int cq = (tid & 63) << 2;   // channel quad base 0..252
    int rs = row_start[i], deg = row_start[i + 1] - rs;

    float a0 = 0.f, a1 = 0.f, a2 = 0.f, a3 = 0.f;
    for (int e = 0; e < deg; ++e) {
        int s = csr_src[rs + e];
        float w = alpha[(size_t)(rs + e) * H_HEADS + h];
        bf16x4 x = *(const bf16x4*)(xh + (size_t)s * HC + h * C_CH + cq);
        a0 = fmaf(w, bf2f(x[0]), a0);
        a1 = fmaf(w, bf2f(x[1]), a1);
        a2 = fmaf(w, bf2f(x[2]), a2);
        a3 = fmaf(w, bf2f(x[3]), a3);
    }
    float sc = inv_denom[i * H_HEADS + h] * 0.25f;  // fold head-mean
    __shared__ float sacc[H_HEADS][C_CH];           // 4 KB
    f32x4 v = {a0 * sc, a1 * sc, a2 * sc, a3 * sc};
    *(f32x4*)&sacc[h][cq] = v;
    __syncthreads();
    int c = tid;
    float o = sacc[0][c] + sacc[1][c] + sacc[2][c] + sacc[3][c];
    out[(size_t)i * C_CH + c] = f2bf(o + bias[c]);
}

extern "C" void kernel_launch(void* const* d_in, const int* in_sizes, int n_in,
                              void* d_out, int out_size, void* d_ws, size_t ws_size,
                              hipStream_t stream)
{
    const float* inp      = (const float*)d_in[0];
    const int*   ei       = (const int*)  d_in[1];
    const float* ln_gamma = (const float*)d_in[2];
    const float* ln_beta  = (const float*)d_in[3];
    const float* W1       = (const float*)d_in[4];
    const float* b1       = (const float*)d_in[5];
    const float* W_gat    = (const float*)d_in[6];
    const float* att_src  = (const float*)d_in[7];
    const float* att_dst  = (const float*)d_in[8];
    const float* bias_gat = (const float*)d_in[9];
    const float* W2       = (const float*)d_in[10];
    const float* b2       = (const float*)d_in[11];

    char* ws = (char*)d_ws;
    __bf16* x_ln_bf    = (__bf16*)(ws);                        //  8 MB
    __bf16* gnn_in_bf  = (__bf16*)(ws + ((size_t) 8 << 20));   //  8 MB
    __bf16* xh_bf      = (__bf16*)(ws + ((size_t)16 << 20));   // 32 MB
    __bf16* gnn_out_bf = (__bf16*)(ws + ((size_t)48 << 20));   //  8 MB
    __bf16* W1_bf      = (__bf16*)(ws + ((size_t)56 << 20));
    __bf16* Wgat_bf    = W1_bf + 65536;
    __bf16* W2_bf      = Wgat_bf + 262144;
    float*  a_src_b    = (float*)(ws + ((size_t)57 << 20));    // 256 KB
    float*  a_dst_b    = a_src_b + (size_t)N_NODES * H_HEADS;  // 256 KB
    float*  alpha      = a_dst_b + (size_t)N_NODES * H_HEADS;  // 1.25 MB
    float*  inv_denom  = alpha + (size_t)ETOT * H_HEADS;       // 256 KB
    int*    deg        = (int*)(inv_denom + (size_t)N_NODES * H_HEADS);
    int*    row_st     = deg + N_NODES;
    int*    cnt        = row_st + N_NODES + 4;
    int*    csr_src    = cnt + N_NODES;

    // weight cast + CSR build
    cast_weights<<<384, 256, 0, stream>>>(W1, W_gat, W2, W1_bf, Wgat_bf, W2_bf);
    hipMemsetAsync(deg, 0, N_NODES * sizeof(int), stream);
    hipMemsetAsync(cnt, 0, N_NODES * sizeof(int), stream);
    hist_kernel<<<(ETOT + 255) / 256, 256, 0, stream>>>(ei, deg);
    scan_kernel<<<1, 1024, 0, stream>>>(deg, row_st);
    scatter_kernel<<<(ETOT + 255) / 256, 256, 0, stream>>>(ei, row_st, cnt, csr_src);

    // dense pipeline
    ln_kernel<<<N_NODES / 4, 256, 0, stream>>>(inp, ln_gamma, ln_beta, x_ln_bf);
    gemm_bf16_nt<<<dim3(D_MODEL / BN, N_NODES / BM), 256, 0, stream>>>(
        x_ln_bf, W1_bf, N_NODES, D_MODEL, D_MODEL, b1, nullptr, nullptr, gnn_in_bf);
    gemm_bf16_nt<<<dim3(HC / BN, N_NODES / BM), 256, 0, stream>>>(
        gnn_in_bf, Wgat_bf, N_NODES, HC, D_MODEL, nullptr, nullptr, nullptr, xh_bf);
    att_logits<<<N_NODES / 4, 256, 0, stream>>>(xh_bf, att_src, att_dst, a_src_b, a_dst_b);
    node_softmax<<<N_NODES / 4, 256, 0, stream>>>(a_src_b, a_dst_b, row_st, csr_src,
                                                  alpha, inv_denom);
    gat_aggregate<<<N_NODES, 256, 0, stream>>>(xh_bf, alpha, inv_denom, row_st, csr_src,
                                               bias_gat, gnn_out_bf);
    gemm_bf16_nt<<<dim3(D_MODEL / BN, N_NODES / BM), 256, 0, stream>>>(
        gnn_out_bf, W2_bf, N_NODES, D_MODEL, D_MODEL, b2, inp, (float*)d_out, nullptr);
}